// Round 21
// baseline (378.515 us; speedup 1.0000x reference)
//
#include <hip/hip_runtime.h>
#include <hip/hip_bf16.h>
#include <math.h>

// Bahdanau attention + reservoir RNN cell.
//  K_prep: fused {Ua_w f32->bf16 B-fragment relayout} + {q = h_prev@Wa^T+b}
//  K2 (R21 = R20 fixed): BM=128 per block, 512 thr / 8 waves, (512,2) ->
//      256-reg budget, 1 block/CU (LDS 128KB). Wave = 128 rows x 32 cols,
//      acc 8x2 = 64 AGPR, TWO column passes (h=0: cols 0..255, h=1: 256..511)
//      -- R20's bug was covering only 256 of 512 cols. Halves B-L2 traffic
//      vs R14 (block reads Ua once per 128 rows) and doubles MFMA:B-load
//      ratio to 8:1; ~100 spare regs allow compiler B-load pipelining.
//  K3: exact combine of 16 partials -> context
//  K4: RNN cell (grid split over o for full-chip coverage)

typedef __attribute__((ext_vector_type(8))) short short8;
typedef __attribute__((ext_vector_type(8))) unsigned short ushort8;
typedef __attribute__((ext_vector_type(4))) float f32x4;

#define S_LEN 2048
#define BDIM 128
#define HDIM 512
#define EDIM 512
#define BM 128
#define NCHUNK (S_LEN / BM)  // 16

__device__ __forceinline__ unsigned short f2bf(float f) {
  unsigned int u = __float_as_uint(f);
  u += 0x7fffu + ((u >> 16) & 1u);  // RNE
  return (unsigned short)(u >> 16);
}

__device__ __forceinline__ float bf2f(unsigned short u) {
  return __uint_as_float(((unsigned int)u) << 16);
}

__device__ __forceinline__ float fast_tanh(float x) {
  float e = __expf(2.0f * x);
  return 1.0f - 2.0f / (e + 1.0f);
}

// Fused prep: blocks 0..127 relayout Ua (f32 -> bf16 fragment order);
// blocks 128..383 compute q = h_prev@Wa^T + Wa_b + Ua_b.
__global__ __launch_bounds__(256) void k_prep(const float* __restrict__ ua_src,
                                              unsigned short* __restrict__ ua_dst,
                                              const float* __restrict__ hp,
                                              const float* __restrict__ Wa,
                                              const float* __restrict__ Wab,
                                              const float* __restrict__ Uab,
                                              float* __restrict__ q) {
  if (blockIdx.x < 128) {
    int tid = blockIdx.x * 256 + threadIdx.x;  // 0..32767
    int ct = tid >> 10;
    int kt = (tid >> 6) & 15;
    int l = tid & 63;
    int col = ct * 16 + (l & 15);
    int k = kt * 32 + (l >> 4) * 8;
    const float4* s = (const float4*)(ua_src + (size_t)col * HDIM + k);
    float4 v0 = s[0], v1 = s[1];
    ushort8 p;
    p[0] = f2bf(v0.x); p[1] = f2bf(v0.y); p[2] = f2bf(v0.z); p[3] = f2bf(v0.w);
    p[4] = f2bf(v1.x); p[5] = f2bf(v1.y); p[6] = f2bf(v1.z); p[7] = f2bf(v1.w);
    *(ushort8*)(ua_dst + (size_t)tid * 8) = p;
  } else {
    int bq = blockIdx.x - 128;
    int b = bq >> 1, oh = bq & 1;
    int o = oh * 256 + threadIdx.x;
    __shared__ float hs[HDIM];
    hs[threadIdx.x] = hp[b * HDIM + threadIdx.x];
    hs[threadIdx.x + 256] = hp[b * HDIM + threadIdx.x + 256];
    __syncthreads();
    const float4* wr = (const float4*)(Wa + (size_t)o * HDIM);
    float acc = 0.f;
#pragma unroll 8
    for (int i = 0; i < HDIM / 4; ++i) {
      float4 v = wr[i];
      acc += v.x * hs[i * 4 + 0] + v.y * hs[i * 4 + 1] + v.z * hs[i * 4 + 2] + v.w * hs[i * 4 + 3];
    }
    q[b * HDIM + o] = acc + Wab[o] + Uab[o];
  }
}

__global__ __launch_bounds__(512, 2) void k_scores_ctx(
    const float* __restrict__ xref, const unsigned short* __restrict__ uab,
    const float* __restrict__ q, const float* __restrict__ va,
    float* __restrict__ mArr, float* __restrict__ lArr, float* __restrict__ cpart) {
  int chunk = blockIdx.x;    // 0..15
  int b = blockIdx.y;
  int tid = threadIdx.x;
  int l = tid & 63;
  int w = tid >> 6;          // 0..7; per pass the wave owns 128 rows x 32 cols
  int c = l & 15, g4 = l >> 4;

  // bf16 tile; logical byte (row,kb) stored at row*1024 + (kb ^ ((row&7)<<4))
  __shared__ __align__(16) unsigned short As[BM * HDIM];  // 128 KB
  __shared__ float sc[BM];
  __shared__ float pl[BM];

  f32x4 acc[8][2];
#pragma unroll
  for (int m = 0; m < 8; ++m)
#pragma unroll
    for (int n = 0; n < 2; ++n) acc[m][n] = f32x4{0.f, 0.f, 0.f, 0.f};

  const float* xb = xref + ((size_t)b * S_LEN + (size_t)chunk * BM) * HDIM;

  // staging (R14 pattern, two row-halves): thread -> rows tid>>3 and tid>>3+64,
  // 8 lanes/row, kb = (tid&7)*16 + p*128; slot-bijective per 8-lane group.
  int srow = tid >> 3, skq = tid & 7;
  int swo = (skq * 16) ^ ((srow & 7) << 4);   // (srow+64)&7 == srow&7
  char* wb0 = (char*)&As[0] + srow * 1024 + swo;
  char* wb1 = (char*)&As[0] + (srow + 64) * 1024 + swo;
  const float* sb0 = xb + (size_t)srow * HDIM + skq * 8;
  const float* sb1 = sb0 + (size_t)64 * HDIM;

  float4 a0, a1, a2, a3, a4, a5, a6, a7;
  short8 bpre[2];

#define LD2(va, vb, sb, p)                                                     \
  {                                                                            \
    va = *(const float4*)((sb) + (p) * 64);                                    \
    vb = *(const float4*)((sb) + (p) * 64 + 4);                                \
  }

#define WR1(va, vb, wb, p)                                                     \
  {                                                                            \
    union { __hip_bfloat162 h[4]; ushort8 s; } u_;                             \
    u_.h[0] = __float22bfloat162_rn(make_float2(va.x, va.y));                  \
    u_.h[1] = __float22bfloat162_rn(make_float2(va.z, va.w));                  \
    u_.h[2] = __float22bfloat162_rn(make_float2(vb.x, vb.y));                  \
    u_.h[3] = __float22bfloat162_rn(make_float2(vb.z, vb.w));                  \
    *(ushort8*)((wb) + (p) * 128) = u_.s;                                      \
  }

#define AFRAGS(kt)                                                             \
    short8 afr_[8];                                                            \
    _Pragma("unroll")                                                          \
    for (int m = 0; m < 8; ++m) {                                              \
      int row = m * 16 + (l & 15);                                             \
      int kb = ((kt) * 64 + (l >> 4) * 16) ^ ((row & 7) << 4);                 \
      afr_[m] = *(const short8*)((const char*)&As[0] + row * 1024 + kb);       \
    }

#define MFMA16(bsrc)                                                           \
    _Pragma("unroll")                                                          \
    for (int m = 0; m < 8; ++m)                                                \
      _Pragma("unroll")                                                        \
      for (int n = 0; n < 2; ++n)                                              \
        acc[m][n] = __builtin_amdgcn_mfma_f32_16x16x32_bf16(afr_[m], bsrc[n],  \
                                                            acc[m][n], 0, 0, 0);

  // cluster for pass h (cols h*256 + w*32 + n*16), k-tile kt
#define CLUSTER(h, kt)                                                         \
  {                                                                            \
    short8 bfr_[2];                                                            \
    _Pragma("unroll")                                                          \
    for (int n = 0; n < 2; ++n) {                                              \
      int ct = (h) * 16 + w * 2 + n;                                           \
      bfr_[n] = *(const short8*)(uab + (((size_t)(ct * 16 + (kt)) * 64 + l) * 8)); \
    }                                                                          \
    AFRAGS(kt)                                                                 \
    MFMA16(bfr_)                                                               \
  }

#define CLUSTER_PRE(kt)                                                        \
  {                                                                            \
    AFRAGS(kt)                                                                 \
    MFMA16(bpre)                                                               \
  }

  // epilogue for pass h: partial-sum scores into sc (atomics accumulate)
#define EPI(h)                                                                 \
  {                                                                            \
    float qf0, qf1, vf0, vf1;                                                  \
    {                                                                          \
      int o0 = (h) * 256 + w * 32 + c, o1 = o0 + 16;                           \
      qf0 = q[b * HDIM + o0]; qf1 = q[b * HDIM + o1];                          \
      vf0 = va[o0]; vf1 = va[o1];                                              \
    }                                                                          \
    _Pragma("unroll")                                                          \
    for (int m = 0; m < 8; ++m) {                                              \
      _Pragma("unroll")                                                        \
      for (int r = 0; r < 4; ++r) {                                            \
        float sum = fast_tanh(acc[m][0][r] + qf0) * vf0 +                      \
                    fast_tanh(acc[m][1][r] + qf1) * vf1;                       \
        sum += __shfl_xor(sum, 1);                                             \
        sum += __shfl_xor(sum, 2);                                             \
        sum += __shfl_xor(sum, 4);                                             \
        sum += __shfl_xor(sum, 8);                                             \
        if (c == 0) atomicAdd(&sc[m * 16 + g4 * 4 + r], sum);                  \
      }                                                                        \
    }                                                                          \
  }

  // stage rows 0..63 then 64..127 (transient regs, conflict-free writes)
  LD2(a0, a1, sb0, 0) LD2(a2, a3, sb0, 1) LD2(a4, a5, sb0, 2) LD2(a6, a7, sb0, 3)
  WR1(a0, a1, wb0, 0) WR1(a2, a3, wb0, 1) WR1(a4, a5, wb0, 2) WR1(a6, a7, wb0, 3)
  LD2(a0, a1, sb0, 4) LD2(a2, a3, sb0, 5) LD2(a4, a5, sb0, 6) LD2(a6, a7, sb0, 7)
  WR1(a0, a1, wb0, 4) WR1(a2, a3, wb0, 5) WR1(a4, a5, wb0, 6) WR1(a6, a7, wb0, 7)
  LD2(a0, a1, sb1, 0) LD2(a2, a3, sb1, 1) LD2(a4, a5, sb1, 2) LD2(a6, a7, sb1, 3)
  WR1(a0, a1, wb1, 0) WR1(a2, a3, wb1, 1) WR1(a4, a5, wb1, 2) WR1(a6, a7, wb1, 3)
  LD2(a0, a1, sb1, 4) LD2(a2, a3, sb1, 5) LD2(a4, a5, sb1, 6) LD2(a6, a7, sb1, 7)
  WR1(a0, a1, wb1, 4) WR1(a2, a3, wb1, 5) WR1(a4, a5, wb1, 6) WR1(a6, a7, wb1, 7)
  if (tid < BM) sc[tid] = 0.f;
  // prefetch pass-0 cluster-0 B fragments
#pragma unroll
  for (int n = 0; n < 2; ++n)
    bpre[n] = *(const short8*)(uab + (((size_t)((w * 2 + n) * 16 + 0) * 64 + l) * 8));
  __syncthreads();

  // ---- pass 0: cols 0..255 ----
  CLUSTER_PRE(0)
  CLUSTER(0, 1)  CLUSTER(0, 2)  CLUSTER(0, 3)
  CLUSTER(0, 4)  CLUSTER(0, 5)  CLUSTER(0, 6)  CLUSTER(0, 7)
  CLUSTER(0, 8)  CLUSTER(0, 9)  CLUSTER(0, 10) CLUSTER(0, 11)
  CLUSTER(0, 12) CLUSTER(0, 13) CLUSTER(0, 14) CLUSTER(0, 15)
  EPI(0)

#pragma unroll
  for (int m = 0; m < 8; ++m)
#pragma unroll
    for (int n = 0; n < 2; ++n) acc[m][n] = f32x4{0.f, 0.f, 0.f, 0.f};

  // ---- pass 1: cols 256..511 ----
  CLUSTER(1, 0)  CLUSTER(1, 1)  CLUSTER(1, 2)  CLUSTER(1, 3)
  CLUSTER(1, 4)  CLUSTER(1, 5)  CLUSTER(1, 6)  CLUSTER(1, 7)
  CLUSTER(1, 8)  CLUSTER(1, 9)  CLUSTER(1, 10) CLUSTER(1, 11)
  CLUSTER(1, 12) CLUSTER(1, 13) CLUSTER(1, 14) CLUSTER(1, 15)
  EPI(1)
  __syncthreads();

  // softmax over the 128 local rows: lane l covers rows l and l+64
  float s0 = sc[l], s1 = sc[l + 64];
  float M = fmaxf(s0, s1);
#pragma unroll
  for (int off = 32; off >= 1; off >>= 1) M = fmaxf(M, __shfl_xor(M, off));
  float p0 = __expf(s0 - M), p1 = __expf(s1 - M);
  float lsum = p0 + p1;
#pragma unroll
  for (int off = 32; off >= 1; off >>= 1) lsum += __shfl_xor(lsum, off);
  if (w == 0) { pl[l] = p0; pl[l + 64] = p1; }
  if (tid == 0) {
    mArr[b * NCHUNK + chunk] = M;
    lArr[b * NCHUNK + chunk] = lsum;
  }
  __syncthreads();

  // partial context from the bf16 LDS tile: thread = one of 512 cols
  {
    int h2 = tid * 2;  // logical kbyte of this col
    const char* base_ = (const char*)&As[0];
    float cacc = 0.f;
#pragma unroll 8
    for (int r = 0; r < BM; ++r) {
      int byte = r * 1024 + (h2 ^ ((r & 7) << 4));
      cacc += pl[r] * bf2f(*(const unsigned short*)(base_ + byte));
    }
    cpart[((size_t)b * NCHUNK + chunk) * HDIM + tid] = cacc;
  }
#undef LD2
#undef WR1
#undef AFRAGS
#undef MFMA16
#undef CLUSTER
#undef CLUSTER_PRE
#undef EPI
}

__global__ __launch_bounds__(512) void k_combine(const float* __restrict__ mArr,
                                                 const float* __restrict__ lArr,
                                                 const float* __restrict__ cpart,
                                                 float* __restrict__ ctx,
                                                 float* __restrict__ out_ctx) {
  int b = blockIdx.x, t = threadIdx.x;
  __shared__ float wf[NCHUNK];
  __shared__ float dinv;
  if (t == 0) {
    float M = mArr[b * NCHUNK];
    for (int i = 1; i < NCHUNK; ++i) M = fmaxf(M, mArr[b * NCHUNK + i]);
    float den = 0.f;
    for (int i = 0; i < NCHUNK; ++i) {
      float f = __expf(mArr[b * NCHUNK + i] - M);
      wf[i] = f;
      den += f * lArr[b * NCHUNK + i];
    }
    dinv = 1.0f / den;
  }
  __syncthreads();
  float s = 0.f;
#pragma unroll
  for (int i = 0; i < NCHUNK; ++i) s += wf[i] * cpart[((size_t)b * NCHUNK + i) * HDIM + t];
  float c = s * dinv;
  ctx[b * HDIM + t] = c;
  out_ctx[b * HDIM + t] = c;
}

__global__ __launch_bounds__(256) void k_rnn(const float* __restrict__ xt,
                                             const float* __restrict__ ctx,
                                             const float* __restrict__ hp,
                                             const float* __restrict__ Wih,
                                             const float* __restrict__ Wihb,
                                             const float* __restrict__ Whh,
                                             const float* __restrict__ Whhb,
                                             float* __restrict__ hout) {
  int b = blockIdx.x, oh = blockIdx.y;
  int o = oh * 256 + threadIdx.x;
  __shared__ float xs[EDIM], cs[HDIM], hs[HDIM];
  xs[threadIdx.x] = xt[b * EDIM + threadIdx.x];
  xs[threadIdx.x + 256] = xt[b * EDIM + threadIdx.x + 256];
  cs[threadIdx.x] = ctx[b * HDIM + threadIdx.x];
  cs[threadIdx.x + 256] = ctx[b * HDIM + threadIdx.x + 256];
  hs[threadIdx.x] = hp[b * HDIM + threadIdx.x];
  hs[threadIdx.x + 256] = hp[b * HDIM + threadIdx.x + 256];
  __syncthreads();
  const float4* wi = (const float4*)(Wih + (size_t)o * (EDIM + HDIM));
  float acc = Wihb[o] + Whhb[o];
#pragma unroll 8
  for (int i = 0; i < EDIM / 4; ++i) {
    float4 v = wi[i];
    acc += v.x * xs[i * 4] + v.y * xs[i * 4 + 1] + v.z * xs[i * 4 + 2] + v.w * xs[i * 4 + 3];
  }
  const float4* wi2 = wi + EDIM / 4;
#pragma unroll 8
  for (int i = 0; i < HDIM / 4; ++i) {
    float4 v = wi2[i];
    acc += v.x * cs[i * 4] + v.y * cs[i * 4 + 1] + v.z * cs[i * 4 + 2] + v.w * cs[i * 4 + 3];
  }
  const float4* wh = (const float4*)(Whh + (size_t)o * HDIM);
#pragma unroll 8
  for (int i = 0; i < HDIM / 4; ++i) {
    float4 v = wh[i];
    acc += v.x * hs[i * 4] + v.y * hs[i * 4 + 1] + v.z * hs[i * 4 + 2] + v.w * hs[i * 4 + 3];
  }
  hout[b * HDIM + o] = tanhf(acc);
}

extern "C" void kernel_launch(void* const* d_in, const int* in_sizes, int n_in,
                              void* d_out, int out_size, void* d_ws, size_t ws_size,
                              hipStream_t stream) {
  const float* x_t    = (const float*)d_in[0];
  const float* x_ref  = (const float*)d_in[1];
  const float* h_prev = (const float*)d_in[2];
  const float* Wa_w   = (const float*)d_in[3];
  const float* Wa_b   = (const float*)d_in[4];
  const float* Ua_w   = (const float*)d_in[5];
  const float* Ua_b   = (const float*)d_in[6];
  const float* Va_w   = (const float*)d_in[7];
  // d_in[8] = Va_b: softmax-invariant, skipped.
  const float* Wih_w  = (const float*)d_in[9];
  const float* Wih_b  = (const float*)d_in[10];
  const float* Whh_w  = (const float*)d_in[11];
  const float* Whh_b  = (const float*)d_in[12];

  char* ws = (char*)d_ws;
  unsigned short* ua_fr = (unsigned short*)ws;   // 512 KB fragment-layout Ua
  float* q     = (float*)(ws + 524288);          // 256 KB
  float* mArr  = (float*)(ws + 786432);          // 8 KB
  float* lArr  = (float*)(ws + 802816);          // 8 KB
  float* cpart = (float*)(ws + 819200);          // 4 MB
  float* ctx   = (float*)(ws + 9207808);         // 256 KB

  float* h_out   = (float*)d_out;
  float* ctx_out = h_out + BDIM * HDIM;

  k_prep<<<dim3(384), dim3(256), 0, stream>>>(Ua_w, ua_fr, h_prev, Wa_w, Wa_b, Ua_b, q);
  k_scores_ctx<<<dim3(NCHUNK, BDIM), dim3(512), 0, stream>>>(x_ref, ua_fr, q, Va_w, mArr, lArr, cpart);
  k_combine<<<dim3(BDIM), dim3(512), 0, stream>>>(mArr, lArr, cpart, ctx, ctx_out);
  k_rnn<<<dim3(BDIM, 2), dim3(256), 0, stream>>>(x_t, ctx, h_prev, Wih_w, Wih_b, Whh_w, Whh_b, h_out);
}

// Round 22
// 288.689 us; speedup vs baseline: 1.3112x; 1.3112x over previous
//
#include <hip/hip_runtime.h>
#include <hip/hip_bf16.h>
#include <math.h>

// Bahdanau attention + reservoir RNN cell.  FINAL = R19 (session best, 289us).
//  K_prep: fused {Ua_w f32->bf16 B-fragment relayout} + {q = h_prev@Wa^T+b}
//  K2: per (b, 64-row chunk): 512 thr / 8 waves, (512,4) -> 2 blocks/CU,
//      4 waves/SIMD, wave = 64 rows x 64 cols, acc 4x4 = 64 AGPR (+~60 arch
//      = full 128 budget). 16-MFMA clusters; B-frags direct from L2;
//      cluster-0 B prefetched pre-barrier. bf16 LDS tile XOR-swizzled,
//      conflict-free write+read. Context from LDS tile.
//      CLOSED CONSTRAINT WEB (R4-R21 measured): reg-pipelining spills
//      (243MB-1.26GB scratch) at any launch_bounds; 1024-thr pinned to
//      64 VGPR; occupancy raises null x3; occupancy cuts -20..-80%
//      (R15/R21); BM=128 two-pass -31% (R21). This config is the
//      feasible optimum of the family at HIP source level.
//  K3: exact combine of 32 partials -> context
//  K4: RNN cell (grid split over o for full-chip coverage)

typedef __attribute__((ext_vector_type(8))) short short8;
typedef __attribute__((ext_vector_type(8))) unsigned short ushort8;
typedef __attribute__((ext_vector_type(4))) float f32x4;

#define S_LEN 2048
#define BDIM 128
#define HDIM 512
#define EDIM 512
#define BM 64
#define NCHUNK (S_LEN / BM)  // 32

__device__ __forceinline__ unsigned short f2bf(float f) {
  unsigned int u = __float_as_uint(f);
  u += 0x7fffu + ((u >> 16) & 1u);  // RNE
  return (unsigned short)(u >> 16);
}

__device__ __forceinline__ float bf2f(unsigned short u) {
  return __uint_as_float(((unsigned int)u) << 16);
}

__device__ __forceinline__ float fast_tanh(float x) {
  float e = __expf(2.0f * x);
  return 1.0f - 2.0f / (e + 1.0f);
}

// Fused prep: blocks 0..127 relayout Ua (f32 -> bf16 fragment order);
// blocks 128..383 compute q = h_prev@Wa^T + Wa_b + Ua_b.
__global__ __launch_bounds__(256) void k_prep(const float* __restrict__ ua_src,
                                              unsigned short* __restrict__ ua_dst,
                                              const float* __restrict__ hp,
                                              const float* __restrict__ Wa,
                                              const float* __restrict__ Wab,
                                              const float* __restrict__ Uab,
                                              float* __restrict__ q) {
  if (blockIdx.x < 128) {
    int tid = blockIdx.x * 256 + threadIdx.x;  // 0..32767
    int ct = tid >> 10;
    int kt = (tid >> 6) & 15;
    int l = tid & 63;
    int col = ct * 16 + (l & 15);
    int k = kt * 32 + (l >> 4) * 8;
    const float4* s = (const float4*)(ua_src + (size_t)col * HDIM + k);
    float4 v0 = s[0], v1 = s[1];
    ushort8 p;
    p[0] = f2bf(v0.x); p[1] = f2bf(v0.y); p[2] = f2bf(v0.z); p[3] = f2bf(v0.w);
    p[4] = f2bf(v1.x); p[5] = f2bf(v1.y); p[6] = f2bf(v1.z); p[7] = f2bf(v1.w);
    *(ushort8*)(ua_dst + (size_t)tid * 8) = p;
  } else {
    int bq = blockIdx.x - 128;
    int b = bq >> 1, oh = bq & 1;
    int o = oh * 256 + threadIdx.x;
    __shared__ float hs[HDIM];
    hs[threadIdx.x] = hp[b * HDIM + threadIdx.x];
    hs[threadIdx.x + 256] = hp[b * HDIM + threadIdx.x + 256];
    __syncthreads();
    const float4* wr = (const float4*)(Wa + (size_t)o * HDIM);
    float acc = 0.f;
#pragma unroll 8
    for (int i = 0; i < HDIM / 4; ++i) {
      float4 v = wr[i];
      acc += v.x * hs[i * 4 + 0] + v.y * hs[i * 4 + 1] + v.z * hs[i * 4 + 2] + v.w * hs[i * 4 + 3];
    }
    q[b * HDIM + o] = acc + Wab[o] + Uab[o];
  }
}

__global__ __launch_bounds__(512, 4) void k_scores_ctx(
    const float* __restrict__ xref, const unsigned short* __restrict__ uab,
    const float* __restrict__ q, const float* __restrict__ va,
    float* __restrict__ mArr, float* __restrict__ lArr, float* __restrict__ cpart) {
  int chunk = blockIdx.x;
  int b = blockIdx.y;
  int tid = threadIdx.x;
  int l = tid & 63;
  int w = tid >> 6;          // 0..7, wave owns 64 rows x 64 cols
  int c = l & 15, g4 = l >> 4;

  // bf16 tile; logical byte (row,kb) stored at row*1024 + (kb ^ ((row&7)<<4))
  __shared__ __align__(16) unsigned short As[BM * HDIM];  // 64 KB
  __shared__ float sc[BM];
  __shared__ float pl[BM];

  f32x4 acc[4][4];
#pragma unroll
  for (int m = 0; m < 4; ++m)
#pragma unroll
    for (int n = 0; n < 4; ++n) acc[m][n] = f32x4{0.f, 0.f, 0.f, 0.f};

  const float* xb = xref + ((size_t)b * S_LEN + (size_t)chunk * BM) * HDIM;

  // staging: thread -> row = tid>>3 (8 lanes/row); per p-chunk the thread
  // covers 8 f32 at kb = (tid&7)*16 + p*128; slot-bijective per 8-lane group.
  int srow = tid >> 3, skq = tid & 7;
  char* wb = (char*)&As[0] + srow * 1024 + ((skq * 16) ^ ((srow & 7) << 4));
  const float* sb = xb + (size_t)srow * HDIM + skq * 8;

  float4 a0, a1, a2, a3, a4, a5, a6, a7;
  short8 bpre[4];

#define LD2(va, vb, p)                                                         \
  {                                                                            \
    va = *(const float4*)(sb + (p) * 64);                                      \
    vb = *(const float4*)(sb + (p) * 64 + 4);                                  \
  }

#define WR1(va, vb, p)                                                         \
  {                                                                            \
    union { __hip_bfloat162 h[4]; ushort8 s; } u_;                             \
    u_.h[0] = __float22bfloat162_rn(make_float2(va.x, va.y));                  \
    u_.h[1] = __float22bfloat162_rn(make_float2(va.z, va.w));                  \
    u_.h[2] = __float22bfloat162_rn(make_float2(vb.x, vb.y));                  \
    u_.h[3] = __float22bfloat162_rn(make_float2(vb.z, vb.w));                  \
    *(ushort8*)(wb + (p) * 128) = u_.s;                                        \
  }

#define AFRAGS(kt)                                                             \
    short8 afr_[4];                                                            \
    _Pragma("unroll")                                                          \
    for (int m = 0; m < 4; ++m) {                                              \
      int row = m * 16 + (l & 15);                                             \
      int kb = ((kt) * 64 + (l >> 4) * 16) ^ ((row & 7) << 4);                 \
      afr_[m] = *(const short8*)((const char*)&As[0] + row * 1024 + kb);       \
    }

#define MFMA16(bsrc)                                                           \
    __builtin_amdgcn_s_setprio(1);                                             \
    _Pragma("unroll")                                                          \
    for (int m = 0; m < 4; ++m)                                                \
      _Pragma("unroll")                                                        \
      for (int n = 0; n < 4; ++n)                                              \
        acc[m][n] = __builtin_amdgcn_mfma_f32_16x16x32_bf16(afr_[m], bsrc[n],  \
                                                            acc[m][n], 0, 0, 0); \
    __builtin_amdgcn_s_setprio(0);

#define CLUSTER(kt)                                                            \
  {                                                                            \
    short8 bfr_[4];                                                            \
    _Pragma("unroll")                                                          \
    for (int n = 0; n < 4; ++n) {                                              \
      int ct = w * 4 + n;                                                      \
      bfr_[n] = *(const short8*)(uab + (((size_t)(ct * 16 + (kt)) * 64 + l) * 8)); \
    }                                                                          \
    AFRAGS(kt)                                                                 \
    MFMA16(bfr_)                                                               \
  }

#define CLUSTER_PRE(kt)                                                        \
  {                                                                            \
    AFRAGS(kt)                                                                 \
    MFMA16(bpre)                                                               \
  }

  // stage the full 64x512 tile: 2 load batches (32 regs transient)
  LD2(a0, a1, 0) LD2(a2, a3, 1) LD2(a4, a5, 2) LD2(a6, a7, 3)
  WR1(a0, a1, 0) WR1(a2, a3, 1) WR1(a4, a5, 2) WR1(a6, a7, 3)
  LD2(a0, a1, 4) LD2(a2, a3, 5) LD2(a4, a5, 6) LD2(a6, a7, 7)
  WR1(a0, a1, 4) WR1(a2, a3, 5) WR1(a4, a5, 6) WR1(a6, a7, 7)
  if (tid < BM) sc[tid] = 0.f;
  // prefetch cluster-0 B fragments (LDS-independent; covers L2 ramp at barrier)
#pragma unroll
  for (int n = 0; n < 4; ++n)
    bpre[n] = *(const short8*)(uab + (((size_t)((w * 4 + n) * 16 + 0) * 64 + l) * 8));
  __syncthreads();

  CLUSTER_PRE(0)
  CLUSTER(1)  CLUSTER(2)  CLUSTER(3)
  CLUSTER(4)  CLUSTER(5)  CLUSTER(6)  CLUSTER(7)
  CLUSTER(8)  CLUSTER(9)  CLUSTER(10) CLUSTER(11)
  CLUSTER(12) CLUSTER(13)

  // q/Va loads hoisted under the last two clusters
  float qf[4], vf[4];
#pragma unroll
  for (int n = 0; n < 4; ++n) {
    int o = w * 64 + n * 16 + c;
    qf[n] = q[b * HDIM + o];
    vf[n] = va[o];
  }
  CLUSTER(14) CLUSTER(15)

  // scores[row] = sum_o tanh(acc + q[o]) * Va[o]
#pragma unroll
  for (int m = 0; m < 4; ++m) {
#pragma unroll
    for (int r = 0; r < 4; ++r) {
      float sum = 0.f;
#pragma unroll
      for (int n = 0; n < 4; ++n) sum += fast_tanh(acc[m][n][r] + qf[n]) * vf[n];
      sum += __shfl_xor(sum, 1);
      sum += __shfl_xor(sum, 2);
      sum += __shfl_xor(sum, 4);
      sum += __shfl_xor(sum, 8);
      if (c == 0) atomicAdd(&sc[m * 16 + g4 * 4 + r], sum);
    }
  }
  __syncthreads();

  // softmax over the 64 local rows (each wave computes identically)
  float M = sc[l];
#pragma unroll
  for (int off = 32; off >= 1; off >>= 1) M = fmaxf(M, __shfl_xor(M, off));
  float pp = __expf(sc[l] - M);
  float lsum = pp;
#pragma unroll
  for (int off = 32; off >= 1; off >>= 1) lsum += __shfl_xor(lsum, off);
  if (tid < BM) pl[tid] = pp;
  if (tid == 0) {
    mArr[b * NCHUNK + chunk] = M;
    lArr[b * NCHUNK + chunk] = lsum;
  }
  __syncthreads();

  // partial context from the bf16 LDS tile: thread = one of 512 cols
  {
    int h2 = tid * 2;  // logical kbyte of this col
    const char* base_ = (const char*)&As[0];
    float cacc = 0.f;
#pragma unroll 8
    for (int r = 0; r < BM; ++r) {
      int byte = r * 1024 + (h2 ^ ((r & 7) << 4));
      cacc += pl[r] * bf2f(*(const unsigned short*)(base_ + byte));
    }
    cpart[((size_t)b * NCHUNK + chunk) * HDIM + tid] = cacc;
  }
#undef LD2
#undef WR1
#undef AFRAGS
#undef MFMA16
#undef CLUSTER
#undef CLUSTER_PRE
}

__global__ __launch_bounds__(512) void k_combine(const float* __restrict__ mArr,
                                                 const float* __restrict__ lArr,
                                                 const float* __restrict__ cpart,
                                                 float* __restrict__ ctx,
                                                 float* __restrict__ out_ctx) {
  int b = blockIdx.x, t = threadIdx.x;
  __shared__ float wf[NCHUNK];
  __shared__ float dinv;
  if (t == 0) {
    float M = mArr[b * NCHUNK];
    for (int i = 1; i < NCHUNK; ++i) M = fmaxf(M, mArr[b * NCHUNK + i]);
    float den = 0.f;
    for (int i = 0; i < NCHUNK; ++i) {
      float f = __expf(mArr[b * NCHUNK + i] - M);
      wf[i] = f;
      den += f * lArr[b * NCHUNK + i];
    }
    dinv = 1.0f / den;
  }
  __syncthreads();
  float s = 0.f;
#pragma unroll
  for (int i = 0; i < NCHUNK; ++i) s += wf[i] * cpart[((size_t)b * NCHUNK + i) * HDIM + t];
  float c = s * dinv;
  ctx[b * HDIM + t] = c;
  out_ctx[b * HDIM + t] = c;
}

__global__ __launch_bounds__(256) void k_rnn(const float* __restrict__ xt,
                                             const float* __restrict__ ctx,
                                             const float* __restrict__ hp,
                                             const float* __restrict__ Wih,
                                             const float* __restrict__ Wihb,
                                             const float* __restrict__ Whh,
                                             const float* __restrict__ Whhb,
                                             float* __restrict__ hout) {
  int b = blockIdx.x, oh = blockIdx.y;
  int o = oh * 256 + threadIdx.x;
  __shared__ float xs[EDIM], cs[HDIM], hs[HDIM];
  xs[threadIdx.x] = xt[b * EDIM + threadIdx.x];
  xs[threadIdx.x + 256] = xt[b * EDIM + threadIdx.x + 256];
  cs[threadIdx.x] = ctx[b * HDIM + threadIdx.x];
  cs[threadIdx.x + 256] = ctx[b * HDIM + threadIdx.x + 256];
  hs[threadIdx.x] = hp[b * HDIM + threadIdx.x];
  hs[threadIdx.x + 256] = hp[b * HDIM + threadIdx.x + 256];
  __syncthreads();
  const float4* wi = (const float4*)(Wih + (size_t)o * (EDIM + HDIM));
  float acc = Wihb[o] + Whhb[o];
#pragma unroll 8
  for (int i = 0; i < EDIM / 4; ++i) {
    float4 v = wi[i];
    acc += v.x * xs[i * 4] + v.y * xs[i * 4 + 1] + v.z * xs[i * 4 + 2] + v.w * xs[i * 4 + 3];
  }
  const float4* wi2 = wi + EDIM / 4;
#pragma unroll 8
  for (int i = 0; i < HDIM / 4; ++i) {
    float4 v = wi2[i];
    acc += v.x * cs[i * 4] + v.y * cs[i * 4 + 1] + v.z * cs[i * 4 + 2] + v.w * cs[i * 4 + 3];
  }
  const float4* wh = (const float4*)(Whh + (size_t)o * HDIM);
#pragma unroll 8
  for (int i = 0; i < HDIM / 4; ++i) {
    float4 v = wh[i];
    acc += v.x * hs[i * 4] + v.y * hs[i * 4 + 1] + v.z * hs[i * 4 + 2] + v.w * hs[i * 4 + 3];
  }
  hout[b * HDIM + o] = tanhf(acc);
}

extern "C" void kernel_launch(void* const* d_in, const int* in_sizes, int n_in,
                              void* d_out, int out_size, void* d_ws, size_t ws_size,
                              hipStream_t stream) {
  const float* x_t    = (const float*)d_in[0];
  const float* x_ref  = (const float*)d_in[1];
  const float* h_prev = (const float*)d_in[2];
  const float* Wa_w   = (const float*)d_in[3];
  const float* Wa_b   = (const float*)d_in[4];
  const float* Ua_w   = (const float*)d_in[5];
  const float* Ua_b   = (const float*)d_in[6];
  const float* Va_w   = (const float*)d_in[7];
  // d_in[8] = Va_b: softmax-invariant, skipped.
  const float* Wih_w  = (const float*)d_in[9];
  const float* Wih_b  = (const float*)d_in[10];
  const float* Whh_w  = (const float*)d_in[11];
  const float* Whh_b  = (const float*)d_in[12];

  char* ws = (char*)d_ws;
  unsigned short* ua_fr = (unsigned short*)ws;   // 512 KB fragment-layout Ua
  float* q     = (float*)(ws + 524288);          // 256 KB
  float* mArr  = (float*)(ws + 786432);          // 16 KB
  float* lArr  = (float*)(ws + 802816);          // 16 KB
  float* cpart = (float*)(ws + 819200);          // 8 MB
  float* ctx   = (float*)(ws + 9207808);         // 256 KB

  float* h_out   = (float*)d_out;
  float* ctx_out = h_out + BDIM * HDIM;

  k_prep<<<dim3(384), dim3(256), 0, stream>>>(Ua_w, ua_fr, h_prev, Wa_w, Wa_b, Ua_b, q);
  k_scores_ctx<<<dim3(NCHUNK, BDIM), dim3(512), 0, stream>>>(x_ref, ua_fr, q, Va_w, mArr, lArr, cpart);
  k_combine<<<dim3(BDIM), dim3(512), 0, stream>>>(mArr, lArr, cpart, ctx, ctx_out);
  k_rnn<<<dim3(BDIM, 2), dim3(256), 0, stream>>>(x_t, ctx, h_prev, Wih_w, Wih_b, Whh_w, Whh_b, h_out);
}